// Round 1
// baseline (296.656 us; speedup 1.0000x reference)
//
#include <hip/hip_runtime.h>

#define TT 28

typedef __attribute__((ext_vector_type(8))) short bf16x8;
typedef __attribute__((ext_vector_type(4))) float f32x4;

__device__ __forceinline__ unsigned fbits(float f){ union{float f; unsigned u;} v; v.f=f; return v.u; }
__device__ __forceinline__ float bitsf(unsigned u){ union{unsigned u; float f;} v; v.u=u; return v.f; }
__device__ __forceinline__ short bf16rnd(float f){ return (short)((fbits(f)+0x8000u)>>16); }

// 32*4096 = 131072 rows. grid = 512 blocks * 4 waves = 2048 wave-groups * 64 rows.
__global__ __launch_bounds__(256, 2) void horizon_kernel(
    const float* __restrict__ x, const float* __restrict__ last_step,
    const float* __restrict__ W_ih, const float* __restrict__ W_hh,
    const float* __restrict__ b_ih, const float* __restrict__ b_hh,
    const float* __restrict__ Wp, const float* __restrict__ bp,
    const float* __restrict__ Wo, const float* __restrict__ bo,
    const float* __restrict__ Wg1, const float* __restrict__ bg1,
    const float* __restrict__ Wg2, const float* __restrict__ bg2,
    const float* __restrict__ log_decay, float* __restrict__ out)
{
    __shared__ __attribute__((aligned(16))) float s_whh[24*8];     // W_hh rows
    __shared__ __attribute__((aligned(16))) float s_gate[28][12];  // [t][0..7]=Wg2 row, [8]=bg2
    __shared__ __attribute__((aligned(16))) float s_wiabc[32];     // (W_ih[o], b_ih[o]+b_hh[o]) o<16
    __shared__ __attribute__((aligned(16))) float s_wb4[32];       // j<8: (W_ih[16+j], b_ih[16+j], b_hh[16+j], Wo[j])
    __shared__ __attribute__((aligned(16))) float s_phA[4][64][20];// per-wave: [row][0..7]=h0, [8..15]=relu(g1)

    const int tid = threadIdx.x;

    // ---- stage uniform weights into LDS ----
    if (tid < 192) s_whh[tid] = W_hh[tid];
    if (tid < 224) s_gate[tid>>3][tid&7] = Wg2[tid];
    if (tid < 28)  s_gate[tid][8] = bg2[tid];
    if (tid < 16){ s_wiabc[2*tid] = W_ih[tid]; s_wiabc[2*tid+1] = b_ih[tid] + b_hh[tid]; }
    if (tid < 8){
        s_wb4[4*tid+0] = W_ih[16+tid];
        s_wb4[4*tid+1] = b_ih[16+tid];
        s_wb4[4*tid+2] = b_hh[16+tid];
        s_wb4[4*tid+3] = Wo[tid];
    }
    __syncthreads();

    const int lane = tid & 63;
    const int wv   = tid >> 6;
    const int c    = lane >> 4;   // k-chunk group (A and B)
    const int rl   = lane & 15;   // A-row within 16 / B-output col
    const int group = blockIdx.x*4 + wv;

    // ---- Phase A: B-fragments for outputs o=rl (o<8 -> Wp, o>=8 -> Wg1) ----
    const float* wrow = (rl < 8) ? (Wp + rl*256) : (Wg1 + (rl-8)*256);
    bf16x8 bfrag[8];
    #pragma unroll
    for (int kk=0; kk<8; ++kk){
        #pragma unroll
        for (int j=0; j<8; ++j) bfrag[kk][j] = bf16rnd(wrow[kk*32 + c*8 + j]);
    }
    const float aBias = (rl < 8) ? bp[rl] : bg1[rl-8];

    #pragma unroll 1
    for (int sub=0; sub<4; ++sub){
        const float* xrow = x + (size_t)(group*64 + sub*16 + rl) * 256;
        f32x4 acc = {0.f, 0.f, 0.f, 0.f};
        #pragma unroll
        for (int kk=0; kk<8; ++kk){
            float4 v0 = *(const float4*)(xrow + kk*32 + c*8);
            float4 v1 = *(const float4*)(xrow + kk*32 + c*8 + 4);
            float xs[8] = {v0.x,v0.y,v0.z,v0.w, v1.x,v1.y,v1.z,v1.w};
            bf16x8 ahi, alo;
            #pragma unroll
            for (int j=0; j<8; ++j){
                unsigned u  = fbits(xs[j]);
                unsigned hb = (u + 0x8000u) & 0xFFFF0000u;   // rounded bf16 "hi" as f32 bits
                ahi[j] = (short)(hb >> 16);
                alo[j] = bf16rnd(xs[j] - bitsf(hb));         // exact residual, rounded to bf16
            }
            acc = __builtin_amdgcn_mfma_f32_16x16x32_bf16(ahi, bfrag[kk], acc, 0, 0, 0);
            acc = __builtin_amdgcn_mfma_f32_16x16x32_bf16(alo, bfrag[kk], acc, 0, 0, 0);
        }
        // D layout: col = lane&15 (=output o), row = (lane>>4)*4 + r
        #pragma unroll
        for (int r=0; r<4; ++r){
            float v = acc[r] + aBias;
            if (rl >= 8) v = fmaxf(v, 0.f);                  // relu only on the gate branch
            s_phA[wv][sub*16 + c*4 + r][rl] = v;
        }
    }
    __syncthreads();

    // ---- Phase B: one lane per row ----
    float4 ha = *(const float4*)&s_phA[wv][lane][0];
    float4 hb = *(const float4*)&s_phA[wv][lane][4];
    float4 qa = *(const float4*)&s_phA[wv][lane][8];
    float4 qb = *(const float4*)&s_phA[wv][lane][12];
    float h[8] = {ha.x,ha.y,ha.z,ha.w, hb.x,hb.y,hb.z,hb.w};
    float q[8] = {qa.x,qa.y,qa.z,qa.w, qb.x,qb.y,qb.z,qb.w};

    const int lrow  = group*64 + lane;
    const float ls0 = last_step[lrow];
    float cur   = ls0;
    const float df = __expf(-__expf(log_decay[0]));
    float decay = 1.f;
    const float boS = bo[0];
    float* orow = out + (size_t)lrow * TT;

    #pragma unroll 1
    for (int t=0; t<TT; ++t){
        __syncthreads();   // uniform; also fences LDS reads so they are not hoisted into registers

        // s[o] = cur*W_ih[o] + (b_ih+b_hh)[o], o<16
        float s[16];
        #pragma unroll
        for (int p=0; p<8; ++p){
            float4 wb = *(const float4*)&s_wiabc[p*4];
            s[2*p+0] = fmaf(cur, wb.x, wb.y);
            s[2*p+1] = fmaf(cur, wb.z, wb.w);
        }
        float gi2[8], bh2[8], wof[8];
        #pragma unroll
        for (int j=0; j<8; ++j){
            float4 wb = *(const float4*)&s_wb4[4*j];
            gi2[j] = fmaf(cur, wb.x, wb.y);  // cur*W_ih[16+j] + b_ih[16+j]
            bh2[j] = wb.z;                   // b_hh[16+j]
            wof[j] = wb.w;                   // Wo[j]
        }
        // s[o] += W_hh[o] . h  for o<16
        #pragma unroll
        for (int o=0; o<16; ++o){
            float4 wa = *(const float4*)&s_whh[o*8];
            float4 wc = *(const float4*)&s_whh[o*8+4];
            float a = s[o];
            a = fmaf(wa.x,h[0],a); a = fmaf(wa.y,h[1],a); a = fmaf(wa.z,h[2],a); a = fmaf(wa.w,h[3],a);
            a = fmaf(wc.x,h[4],a); a = fmaf(wc.y,h[5],a); a = fmaf(wc.z,h[6],a); a = fmaf(wc.w,h[7],a);
            s[o] = a;
        }
        float nn[8], zz[8];
        #pragma unroll
        for (int o=0; o<8; ++o){
            float4 wa = *(const float4*)&s_whh[(16+o)*8];
            float4 wc = *(const float4*)&s_whh[(16+o)*8+4];
            float g = bh2[o];                // gh2 includes b_hh
            g = fmaf(wa.x,h[0],g); g = fmaf(wa.y,h[1],g); g = fmaf(wa.z,h[2],g); g = fmaf(wa.w,h[3],g);
            g = fmaf(wc.x,h[4],g); g = fmaf(wc.y,h[5],g); g = fmaf(wc.z,h[6],g); g = fmaf(wc.w,h[7],g);
            float r  = 1.f/(1.f + __expf(-s[o]));       // sigmoid
            float un = fmaf(r, g, gi2[o]);
            float e2 = __expf(2.f*un);
            nn[o] = 1.f - 2.f/(e2 + 1.f);               // tanh, saturates correctly at +/-inf
            zz[o] = 1.f/(1.f + __expf(-s[8+o]));
        }
        float pred = boS;
        #pragma unroll
        for (int j=0; j<8; ++j){
            h[j] = fmaf(zz[j], h[j]-nn[j], nn[j]);      // (1-z)*n + z*h
            pred = fmaf(h[j], wof[j], pred);
        }
        // gate_t = sigmoid(Wg2[t].q + bg2[t])
        float4 ga = *(const float4*)&s_gate[t][0];
        float4 gb = *(const float4*)&s_gate[t][4];
        float gl = s_gate[t][8];
        gl = fmaf(ga.x,q[0],gl); gl = fmaf(ga.y,q[1],gl); gl = fmaf(ga.z,q[2],gl); gl = fmaf(ga.w,q[3],gl);
        gl = fmaf(gb.x,q[4],gl); gl = fmaf(gb.y,q[5],gl); gl = fmaf(gb.z,q[6],gl); gl = fmaf(gb.w,q[7],gl);
        float gate = 1.f/(1.f + __expf(-gl));

        decay *= df;
        float dp = ls0 * decay;                          // last_step * exp(-exp(ld)*(t+1))
        orow[t] = fmaf(gate, pred - dp, dp);             // gate*gru + (1-gate)*decay_pred
        cur = pred;
    }
}

extern "C" void kernel_launch(void* const* d_in, const int* in_sizes, int n_in,
                              void* d_out, int out_size, void* d_ws, size_t ws_size,
                              hipStream_t stream)
{
    const float* x         = (const float*)d_in[0];
    const float* last_step = (const float*)d_in[1];
    const float* W_ih      = (const float*)d_in[2];
    const float* W_hh      = (const float*)d_in[3];
    const float* b_ih      = (const float*)d_in[4];
    const float* b_hh      = (const float*)d_in[5];
    const float* Wp        = (const float*)d_in[6];
    const float* bp        = (const float*)d_in[7];
    const float* Wo        = (const float*)d_in[8];
    const float* bo        = (const float*)d_in[9];
    const float* Wg1       = (const float*)d_in[10];
    const float* bg1       = (const float*)d_in[11];
    const float* Wg2       = (const float*)d_in[12];
    const float* bg2       = (const float*)d_in[13];
    const float* log_decay = (const float*)d_in[14];

    hipLaunchKernelGGL(horizon_kernel, dim3(512), dim3(256), 0, stream,
                       x, last_step, W_ih, W_hh, b_ih, b_hh, Wp, bp, Wo, bo,
                       Wg1, bg1, Wg2, bg2, log_decay, (float*)d_out);
}

// Round 2
// 279.510 us; speedup vs baseline: 1.0613x; 1.0613x over previous
//
#include <hip/hip_runtime.h>

#define TT 28

typedef __attribute__((ext_vector_type(8))) short bf16x8;
typedef __attribute__((ext_vector_type(4))) float f32x4;

__device__ __forceinline__ unsigned fbits(float f){ union{float f; unsigned u;} v; v.f=f; return v.u; }
__device__ __forceinline__ float bitsf(unsigned u){ union{unsigned u; float f;} v; v.u=u; return v.f; }
__device__ __forceinline__ short bf16rnd(float f){ return (short)((fbits(f)+0x8000u)>>16); }

// 32*4096 = 131072 rows. grid = 512 blocks * 4 waves = 2048 waves * 64 rows.
__global__ __launch_bounds__(256) __attribute__((amdgpu_waves_per_eu(2, 2)))
void horizon_kernel(
    const float* __restrict__ x, const float* __restrict__ last_step,
    const float* __restrict__ W_ih, const float* __restrict__ W_hh,
    const float* __restrict__ b_ih, const float* __restrict__ b_hh,
    const float* __restrict__ Wp, const float* __restrict__ bp,
    const float* __restrict__ Wo, const float* __restrict__ bo,
    const float* __restrict__ Wg1, const float* __restrict__ bg1,
    const float* __restrict__ Wg2, const float* __restrict__ bg2,
    const float* __restrict__ log_decay, float* __restrict__ out)
{
    __shared__ __attribute__((aligned(16))) float s_whh[24*8];     // all W_hh rows
    __shared__ __attribute__((aligned(16))) float s_gate[28][12];  // [t][0..7]=Wg2 row, [8]=bg2
    __shared__ __attribute__((aligned(16))) float s_wiabc[32];     // (W_ih[o], b_ih[o]+b_hh[o]) o<16
    __shared__ __attribute__((aligned(16))) float s_wb4[32];       // j<8: (W_ih[16+j], b_ih[16+j], b_hh[16+j], Wo[j])
    // per-wave dynamic region: Phase A uses [row*20 + o] (<=1280), t-loop uses [row*29 + t] (<=1855)
    __shared__ __attribute__((aligned(16))) float s_dyn[4][64*29];

    const int tid = threadIdx.x;

    // ---- stage uniform weights into LDS (then ONE barrier) ----
    if (tid < 192) s_whh[tid] = W_hh[tid];
    if (tid < 224) s_gate[tid>>3][tid&7] = Wg2[tid];
    if (tid < 28)  s_gate[tid][8] = bg2[tid];
    if (tid < 16){ s_wiabc[2*tid] = W_ih[tid]; s_wiabc[2*tid+1] = b_ih[tid] + b_hh[tid]; }
    if (tid < 8){
        s_wb4[4*tid+0] = W_ih[16+tid];
        s_wb4[4*tid+1] = b_ih[16+tid];
        s_wb4[4*tid+2] = b_hh[16+tid];
        s_wb4[4*tid+3] = Wo[tid];
    }
    __syncthreads();   // the only block-wide barrier; everything below is per-wave

    const int lane = tid & 63;
    const int wv   = tid >> 6;
    const int c    = lane >> 4;   // k-chunk group (A and B)
    const int rl   = lane & 15;   // A-row within 16 / B-output col
    const int group = blockIdx.x*4 + wv;
    float* dyn = &s_dyn[wv][0];

    // ---- Phase A: h0 = x@Wp^T + bp ; q = relu(x@Wg1^T + bg1), via bf16 hi/lo MFMA ----
    const float* wrow = (rl < 8) ? (Wp + rl*256) : (Wg1 + (rl-8)*256);
    bf16x8 bfrag[8];
    #pragma unroll
    for (int kk=0; kk<8; ++kk){
        #pragma unroll
        for (int j=0; j<8; ++j) bfrag[kk][j] = bf16rnd(wrow[kk*32 + c*8 + j]);
    }
    const float aBias = (rl < 8) ? bp[rl] : bg1[rl-8];

    #pragma unroll 1
    for (int sub=0; sub<4; ++sub){
        const float* xrow = x + (size_t)(group*64 + sub*16 + rl) * 256;
        f32x4 acc = {0.f, 0.f, 0.f, 0.f};
        #pragma unroll
        for (int kk=0; kk<8; ++kk){
            float4 v0 = *(const float4*)(xrow + kk*32 + c*8);
            float4 v1 = *(const float4*)(xrow + kk*32 + c*8 + 4);
            float xs[8] = {v0.x,v0.y,v0.z,v0.w, v1.x,v1.y,v1.z,v1.w};
            bf16x8 ahi, alo;
            #pragma unroll
            for (int j=0; j<8; ++j){
                unsigned u  = fbits(xs[j]);
                unsigned hb = (u + 0x8000u) & 0xFFFF0000u;   // rounded bf16 "hi" as f32 bits
                ahi[j] = (short)(hb >> 16);
                alo[j] = bf16rnd(xs[j] - bitsf(hb));         // residual, rounded to bf16
            }
            acc = __builtin_amdgcn_mfma_f32_16x16x32_bf16(ahi, bfrag[kk], acc, 0, 0, 0);
            acc = __builtin_amdgcn_mfma_f32_16x16x32_bf16(alo, bfrag[kk], acc, 0, 0, 0);
        }
        // D layout: col = lane&15 (= output o), row = (lane>>4)*4 + r
        #pragma unroll
        for (int r=0; r<4; ++r){
            float v = acc[r] + aBias;
            if (rl >= 8) v = fmaxf(v, 0.f);                  // relu only on gate branch
            dyn[(sub*16 + c*4 + r)*20 + rl] = v;
        }
    }
    // per-wave region: same-wave LDS ops are ordered; no barrier needed

    // ---- gather per-row state (1 lane = 1 row) ----
    float h[8], q[8];
    #pragma unroll
    for (int j=0; j<8; ++j){ h[j] = dyn[lane*20 + j]; q[j] = dyn[lane*20 + 8 + j]; }

    // ---- hoist loop-invariant weights into registers (128 floats) ----
    float w1[16], bb1[16];
    #pragma unroll
    for (int p=0; p<8; ++p){
        float4 wb = *(const float4*)&s_wiabc[p*4];
        w1[2*p] = wb.x; bb1[2*p] = wb.y; w1[2*p+1] = wb.z; bb1[2*p+1] = wb.w;
    }
    float w2[8], bi2[8], bh2c[8], wo8[8];
    #pragma unroll
    for (int j=0; j<8; ++j){
        float4 wb = *(const float4*)&s_wb4[4*j];
        w2[j] = wb.x; bi2[j] = wb.y; bh2c[j] = wb.z; wo8[j] = wb.w;
    }
    float whn[8][8];   // W_hh rows 16..23 (n-gate)
    #pragma unroll
    for (int o=0; o<8; ++o){
        float4 wa = *(const float4*)&s_whh[(16+o)*8];
        float4 wc = *(const float4*)&s_whh[(16+o)*8+4];
        whn[o][0]=wa.x; whn[o][1]=wa.y; whn[o][2]=wa.z; whn[o][3]=wa.w;
        whn[o][4]=wc.x; whn[o][5]=wc.y; whn[o][6]=wc.z; whn[o][7]=wc.w;
    }

    const int lrow  = group*64 + lane;
    const float ls0 = last_step[lrow];
    float cur   = ls0;
    const float df = __expf(-__expf(log_decay[0]));
    float decay = 1.f;
    const float boS = bo[0];

    #pragma unroll 1
    for (int t=0; t<TT; ++t){
        asm volatile("" ::: "memory");   // LICM fence: keep r/z W_hh rows as per-step LDS reads

        // s[o] = cur*W_ih[o] + (b_ih+b_hh)[o] + W_hh[o].h, o<16 (r,z pre-activations)
        float s[16];
        #pragma unroll
        for (int o=0; o<16; ++o) s[o] = fmaf(cur, w1[o], bb1[o]);
        #pragma unroll
        for (int o=0; o<16; ++o){
            float4 wa = *(const float4*)&s_whh[o*8];
            float4 wc = *(const float4*)&s_whh[o*8+4];
            float a = s[o];
            a = fmaf(wa.x,h[0],a); a = fmaf(wa.y,h[1],a); a = fmaf(wa.z,h[2],a); a = fmaf(wa.w,h[3],a);
            a = fmaf(wc.x,h[4],a); a = fmaf(wc.y,h[5],a); a = fmaf(wc.z,h[6],a); a = fmaf(wc.w,h[7],a);
            s[o] = a;
        }
        float nn[8], zz[8];
        #pragma unroll
        for (int o=0; o<8; ++o){
            float g = bh2c[o];                        // b_hh[16+o] + W_hh_n[o].h
            g = fmaf(whn[o][0],h[0],g); g = fmaf(whn[o][1],h[1],g);
            g = fmaf(whn[o][2],h[2],g); g = fmaf(whn[o][3],h[3],g);
            g = fmaf(whn[o][4],h[4],g); g = fmaf(whn[o][5],h[5],g);
            g = fmaf(whn[o][6],h[6],g); g = fmaf(whn[o][7],h[7],g);
            float r  = 1.f/(1.f + __expf(-s[o]));     // sigmoid
            float un = fmaf(r, g, fmaf(cur, w2[o], bi2[o]));
            float e2 = __expf(2.f*un);
            nn[o] = 1.f - 2.f/(e2 + 1.f);             // tanh with correct saturation
            zz[o] = 1.f/(1.f + __expf(-s[8+o]));
        }
        float pred = boS;
        #pragma unroll
        for (int j=0; j<8; ++j){
            h[j] = fmaf(zz[j], h[j]-nn[j], nn[j]);    // (1-z)*n + z*h
            pred = fmaf(h[j], wo8[j], pred);
        }
        // gate_t = sigmoid(Wg2[t].q + bg2[t])
        float4 ga = *(const float4*)&s_gate[t][0];
        float4 gb = *(const float4*)&s_gate[t][4];
        float gl = s_gate[t][8];
        gl = fmaf(ga.x,q[0],gl); gl = fmaf(ga.y,q[1],gl); gl = fmaf(ga.z,q[2],gl); gl = fmaf(ga.w,q[3],gl);
        gl = fmaf(gb.x,q[4],gl); gl = fmaf(gb.y,q[5],gl); gl = fmaf(gb.z,q[6],gl); gl = fmaf(gb.w,q[7],gl);
        float gate = 1.f/(1.f + __expf(-gl));

        decay *= df;
        float dp = ls0 * decay;                       // last_step * exp(-exp(ld)*(t+1))
        dyn[lane*29 + t] = fmaf(gate, pred - dp, dp); // stride-29: (29*lane+t)%32 -> 2 lanes/bank, free
        cur = pred;
    }

    // ---- final coalesced write: 28 floats/row as 7 dwordx4 ----
    float o28[TT];
    #pragma unroll
    for (int t=0; t<TT; ++t) o28[t] = dyn[lane*29 + t];
    float* orow = out + (size_t)lrow * TT;
    #pragma unroll
    for (int i=0; i<7; ++i){
        float4 v = make_float4(o28[4*i], o28[4*i+1], o28[4*i+2], o28[4*i+3]);
        *(float4*)(orow + 4*i) = v;
    }
}

extern "C" void kernel_launch(void* const* d_in, const int* in_sizes, int n_in,
                              void* d_out, int out_size, void* d_ws, size_t ws_size,
                              hipStream_t stream)
{
    const float* x         = (const float*)d_in[0];
    const float* last_step = (const float*)d_in[1];
    const float* W_ih      = (const float*)d_in[2];
    const float* W_hh      = (const float*)d_in[3];
    const float* b_ih      = (const float*)d_in[4];
    const float* b_hh      = (const float*)d_in[5];
    const float* Wp        = (const float*)d_in[6];
    const float* bp        = (const float*)d_in[7];
    const float* Wo        = (const float*)d_in[8];
    const float* bo        = (const float*)d_in[9];
    const float* Wg1       = (const float*)d_in[10];
    const float* bg1       = (const float*)d_in[11];
    const float* Wg2       = (const float*)d_in[12];
    const float* bg2       = (const float*)d_in[13];
    const float* log_decay = (const float*)d_in[14];

    hipLaunchKernelGGL(horizon_kernel, dim3(512), dim3(256), 0, stream,
                       x, last_step, W_ih, W_hh, b_ih, b_hh, Wp, bp, Wo, bo,
                       Wg1, bg1, Wg2, bg2, log_decay, (float*)d_out);
}

// Round 4
// 258.507 us; speedup vs baseline: 1.1476x; 1.0812x over previous
//
#include <hip/hip_runtime.h>

#define TT 28
#define L2E 1.4426950408889634f

typedef __attribute__((ext_vector_type(8))) short bf16x8;
typedef __attribute__((ext_vector_type(4))) float f32x4;
typedef _Float16 h2 __attribute__((ext_vector_type(2)));
typedef __fp16 fp16x2 __attribute__((ext_vector_type(2)));

__device__ __forceinline__ unsigned fbits(float f){ union{float f; unsigned u;} v; v.f=f; return v.u; }
__device__ __forceinline__ float bitsf(unsigned u){ union{unsigned u; float f;} v; v.u=u; return v.f; }
__device__ __forceinline__ short bf16rnd(float f){ return (short)((fbits(f)+0x8000u)>>16); }

__device__ __forceinline__ h2 PKH2(float a, float b){
    fp16x2 t = __builtin_amdgcn_cvt_pkrtz(a, b);   // v_cvt_pkrtz_f16_f32
    return __builtin_bit_cast(h2, t);
}

#if __has_builtin(__builtin_amdgcn_fdot2)
#define FDOT2(a,b,c) __builtin_amdgcn_fdot2((a),(b),(c),false)
#else
__device__ __forceinline__ float FDOT2(h2 a, h2 b, float c){
    return fmaf((float)a.x,(float)b.x, fmaf((float)a.y,(float)b.y,(c)));
}
#endif
#if __has_builtin(__builtin_amdgcn_exp2f)
#define EXP2(x) __builtin_amdgcn_exp2f(x)
#else
#define EXP2(x) exp2f(x)
#endif
#if __has_builtin(__builtin_amdgcn_rcpf)
#define RCP(x) __builtin_amdgcn_rcpf(x)
#else
#define RCP(x) (1.f/(x))
#endif

// 32*4096 = 131072 rows. grid = 512 blocks * 4 waves = 2048 waves * 64 rows (1 lane = 1 row).
__global__ __launch_bounds__(256) __attribute__((amdgpu_waves_per_eu(2, 2)))
void horizon_kernel(
    const float* __restrict__ x, const float* __restrict__ last_step,
    const float* __restrict__ W_ih, const float* __restrict__ W_hh,
    const float* __restrict__ b_ih, const float* __restrict__ b_hh,
    const float* __restrict__ Wp, const float* __restrict__ bp,
    const float* __restrict__ Wo, const float* __restrict__ bo,
    const float* __restrict__ Wg1, const float* __restrict__ bg1,
    const float* __restrict__ Wg2, const float* __restrict__ bg2,
    const float* __restrict__ log_decay, float* __restrict__ out)
{
    // r/z rows pre-scaled by log2e, n rows by 2*log2e (folds exp->exp2 rescale into weights)
    __shared__ __attribute__((aligned(16))) float s_whh[24*8];
    __shared__ __attribute__((aligned(16))) float s_gate[28][12];  // [t][0..7]=Wg2*log2e, [8]=bg2*log2e
    __shared__ __attribute__((aligned(16))) float s_wiabc[32];     // (W_ih[o], b_ih[o]+b_hh[o])*log2e, o<16
    __shared__ __attribute__((aligned(16))) float s_wb4[32];       // j<8: (W_ih,b_ih,b_hh)[16+j]*2log2e, Wo[j]
    // per-wave: Phase A parked at [row*20+o] (<=1280); t-loop out-stash at [row*29+t] (<=1855)
    __shared__ __attribute__((aligned(16))) float s_dyn[4][64*29];

    const int tid = threadIdx.x;

    // ---- stage uniform weights into LDS (one barrier) ----
    if (tid < 192) s_whh[tid] = W_hh[tid] * (tid < 128 ? L2E : 2.0f*L2E);
    if (tid < 224) s_gate[tid>>3][tid&7] = Wg2[tid] * L2E;
    if (tid < 28)  s_gate[tid][8] = bg2[tid] * L2E;
    if (tid < 16){ s_wiabc[2*tid] = W_ih[tid]*L2E; s_wiabc[2*tid+1] = (b_ih[tid] + b_hh[tid])*L2E; }
    if (tid < 8){
        s_wb4[4*tid+0] = W_ih[16+tid]*2.0f*L2E;
        s_wb4[4*tid+1] = b_ih[16+tid]*2.0f*L2E;
        s_wb4[4*tid+2] = b_hh[16+tid]*2.0f*L2E;
        s_wb4[4*tid+3] = Wo[tid];
    }
    __syncthreads();   // only block-wide barrier; all later LDS use is per-wave

    const int lane = tid & 63;
    const int wv   = tid >> 6;
    const int c    = lane >> 4;   // k-chunk group
    const int rl   = lane & 15;   // A-row within 16 / B-output col
    const int group = blockIdx.x*4 + wv;
    float* dyn = &s_dyn[wv][0];

    // ---- Phase A: h0 = x@Wp^T + bp ; q = relu(x@Wg1^T + bg1), bf16 hi/lo MFMA ----
    const float* wrow = (rl < 8) ? (Wp + rl*256) : (Wg1 + (rl-8)*256);
    bf16x8 bfrag[8];
    #pragma unroll
    for (int kk=0; kk<8; ++kk){
        #pragma unroll
        for (int j=0; j<8; ++j) bfrag[kk][j] = bf16rnd(wrow[kk*32 + c*8 + j]);
    }
    const float aBias = (rl < 8) ? bp[rl] : bg1[rl-8];

    #pragma unroll 2
    for (int sub=0; sub<4; ++sub){
        const float* xrow = x + (size_t)(group*64 + sub*16 + rl) * 256;
        f32x4 acc = {0.f, 0.f, 0.f, 0.f};
        #pragma unroll
        for (int kk=0; kk<8; ++kk){
            float4 v0 = *(const float4*)(xrow + kk*32 + c*8);
            float4 v1 = *(const float4*)(xrow + kk*32 + c*8 + 4);
            float xs[8] = {v0.x,v0.y,v0.z,v0.w, v1.x,v1.y,v1.z,v1.w};
            bf16x8 ahi, alo;
            #pragma unroll
            for (int j=0; j<8; ++j){
                unsigned u  = fbits(xs[j]);
                unsigned hb = (u + 0x8000u) & 0xFFFF0000u;   // rounded bf16 "hi" as f32 bits
                ahi[j] = (short)(hb >> 16);
                alo[j] = bf16rnd(xs[j] - bitsf(hb));         // residual, rounded to bf16
            }
            acc = __builtin_amdgcn_mfma_f32_16x16x32_bf16(ahi, bfrag[kk], acc, 0, 0, 0);
            acc = __builtin_amdgcn_mfma_f32_16x16x32_bf16(alo, bfrag[kk], acc, 0, 0, 0);
        }
        // D layout: col = lane&15 (= output o), row = (lane>>4)*4 + r
        #pragma unroll
        for (int r=0; r<4; ++r){
            float v = acc[r] + aBias;
            if (rl >= 8) v = fmaxf(v, 0.f);
            dyn[(sub*16 + c*4 + r)*20 + rl] = v;
        }
    }
    // same-wave LDS ordering: no barrier needed

    // ---- gather per-row state (1 lane = 1 row) ----
    float h[8], q[8];
    #pragma unroll
    for (int j=0; j<8; ++j){ h[j] = dyn[lane*20 + j]; q[j] = dyn[lane*20 + 8 + j]; }

    // ---- all weights -> registers; W_hh as f16 pairs (96 VGPRs) for v_dot2 ----
    float w1[16], bb1[16];
    #pragma unroll
    for (int p=0; p<8; ++p){
        float4 wb = *(const float4*)&s_wiabc[p*4];
        w1[2*p] = wb.x; bb1[2*p] = wb.y; w1[2*p+1] = wb.z; bb1[2*p+1] = wb.w;
    }
    float w2[8], bi2[8], bh2c[8], wo8[8];
    #pragma unroll
    for (int j=0; j<8; ++j){
        float4 wb = *(const float4*)&s_wb4[4*j];
        w2[j] = wb.x; bi2[j] = wb.y; bh2c[j] = wb.z; wo8[j] = wb.w;
    }
    h2 whh2[24][4];
    #pragma unroll
    for (int o=0; o<24; ++o){
        float4 wa = *(const float4*)&s_whh[o*8];
        float4 wc = *(const float4*)&s_whh[o*8+4];
        whh2[o][0] = PKH2(wa.x, wa.y); whh2[o][1] = PKH2(wa.z, wa.w);
        whh2[o][2] = PKH2(wc.x, wc.y); whh2[o][3] = PKH2(wc.z, wc.w);
    }

    const int lrow  = group*64 + lane;
    const float ls0 = last_step[lrow];
    float cur   = ls0;
    const float df = __expf(-__expf(log_decay[0]));
    float decay = 1.f;
    const float boS = bo[0];

    #pragma unroll 1
    for (int t=0; t<TT; ++t){
        h2 hh[4];
        #pragma unroll
        for (int k=0; k<4; ++k) hh[k] = PKH2(h[2*k], h[2*k+1]);

        // r/z pre-activations (already *log2e): s[o] = cur*w1+bb1 + Whh[o].h
        float s[16];
        #pragma unroll
        for (int o=0; o<16; ++o){
            float a = fmaf(cur, w1[o], bb1[o]);
            #pragma unroll
            for (int k=0; k<4; ++k) a = FDOT2(hh[k], whh2[o][k], a);
            s[o] = a;
        }
        float nn[8], zz[8];
        #pragma unroll
        for (int o=0; o<8; ++o){
            float g = bh2c[o];                         // n-gate dot (already *2log2e)
            #pragma unroll
            for (int k=0; k<4; ++k) g = FDOT2(hh[k], whh2[16+o][k], g);
            float r  = RCP(1.f + EXP2(-s[o]));         // sigmoid (s pre-scaled)
            float un = fmaf(r, g, fmaf(cur, w2[o], bi2[o]));
            float e2 = EXP2(un);                       // e^(2*un_raw)
            nn[o] = fmaf(-2.f, RCP(e2 + 1.f), 1.f);    // tanh, saturates correctly
            zz[o] = RCP(1.f + EXP2(-s[8+o]));
        }
        float pred = boS;
        #pragma unroll
        for (int j=0; j<8; ++j){
            h[j] = fmaf(zz[j], h[j]-nn[j], nn[j]);     // (1-z)*n + z*h
            pred = fmaf(h[j], wo8[j], pred);
        }
        // gate_t = sigmoid(Wg2[t].q + bg2[t]) — only remaining in-loop LDS reads (broadcast)
        float4 ga = *(const float4*)&s_gate[t][0];
        float4 gb = *(const float4*)&s_gate[t][4];
        float gl = s_gate[t][8];
        gl = fmaf(ga.x,q[0],gl); gl = fmaf(ga.y,q[1],gl); gl = fmaf(ga.z,q[2],gl); gl = fmaf(ga.w,q[3],gl);
        gl = fmaf(gb.x,q[4],gl); gl = fmaf(gb.y,q[5],gl); gl = fmaf(gb.z,q[6],gl); gl = fmaf(gb.w,q[7],gl);
        float gate = RCP(1.f + EXP2(-gl));

        decay *= df;
        float dp = ls0 * decay;                        // last_step * exp(-exp(ld)*(t+1))
        dyn[lane*29 + t] = fmaf(gate, pred - dp, dp);  // stride-29: 2 lanes/bank, free
        cur = pred;
    }

    // ---- final coalesced write: 28 floats/row as 7 dwordx4 ----
    float o28[TT];
    #pragma unroll
    for (int t=0; t<TT; ++t) o28[t] = dyn[lane*29 + t];
    float* orow = out + (size_t)lrow * TT;
    #pragma unroll
    for (int i=0; i<7; ++i){
        float4 v = make_float4(o28[4*i], o28[4*i+1], o28[4*i+2], o28[4*i+3]);
        *(float4*)(orow + 4*i) = v;
    }
}

extern "C" void kernel_launch(void* const* d_in, const int* in_sizes, int n_in,
                              void* d_out, int out_size, void* d_ws, size_t ws_size,
                              hipStream_t stream)
{
    const float* x         = (const float*)d_in[0];
    const float* last_step = (const float*)d_in[1];
    const float* W_ih      = (const float*)d_in[2];
    const float* W_hh      = (const float*)d_in[3];
    const float* b_ih      = (const float*)d_in[4];
    const float* b_hh      = (const float*)d_in[5];
    const float* Wp        = (const float*)d_in[6];
    const float* bp        = (const float*)d_in[7];
    const float* Wo        = (const float*)d_in[8];
    const float* bo        = (const float*)d_in[9];
    const float* Wg1       = (const float*)d_in[10];
    const float* bg1       = (const float*)d_in[11];
    const float* Wg2       = (const float*)d_in[12];
    const float* bg2       = (const float*)d_in[13];
    const float* log_decay = (const float*)d_in[14];

    hipLaunchKernelGGL(horizon_kernel, dim3(512), dim3(256), 0, stream,
                       x, last_step, W_ih, W_hh, b_ih, b_hh, Wp, bp, Wo, bo,
                       Wg1, bg1, Wg2, bg2, log_decay, (float*)d_out);
}